// Round 10
// baseline (45.979 us; speedup 1.0000x reference)
//
#include <hip/hip_runtime.h>

#define B_ 2
#define A_ 16384
#define C_ 15
#define G_ 16
#define D2Rf 0.017453292519943295f
#define ENC_HALF 0xBF000000u   // enc(0.5f)
#define ENC_04   0xBECCCCCDu   // enc(0.4f)
#define NSEG 128               // gate blocks / segments
#define HB_ 256                // heavy blocks
#define LB_ 128                // loss blocks
#define SEGCAP 4096            // per-segment worklist capacity (256*16 max)

__device__ __forceinline__ unsigned enc_f32(float f) {
    unsigned u = __float_as_uint(f);
    return u ^ ((u >> 31) ? 0xFFFFFFFFu : 0x80000000u);
}

// ---------------------------------------------------------------------------
// Rotated IoU. Identical arithmetic to the reference EXCEPT the sort key:
// atan2f replaced by an order-equivalent pseudo-angle (monotone in true
// angle over (-pi, pi], (0,0)->0 like atan2). Tie-sets can differ from fp32
// atan2 only at rounding boundaries of near-identical rays -> area delta ~0.
// ---------------------------------------------------------------------------
__device__ __forceinline__ float pseudo_angle(float y, float x) {
    float d = fabsf(x) + fabsf(y);
    float r = y / d;                      // NaN when d==0, fixed below
    float p = (x >= 0.f) ? r : ((y >= 0.f) ? 2.f - r : -2.f - r);
    return (d == 0.f) ? 0.f : p;
}

__device__ __forceinline__ void rect_corners5(const float* b, float X[4], float Y[4],
                                              float* cth, float* sth) {
    float th = b[4] * D2Rf;
    float c = cosf(th), s = sinf(th);
    *cth = c; *sth = s;
    const float SX[4] = {-1.f, 1.f, 1.f, -1.f};
    const float SY[4] = {-1.f, -1.f, 1.f, 1.f};
    float hw = 0.5f * b[2], hh = 0.5f * b[3];
#pragma unroll
    for (int i = 0; i < 4; ++i) {
        float dx = hw * SX[i];
        float dy = hh * SY[i];
        X[i] = b[0] + dx * c - dy * s;
        Y[i] = b[1] + dx * s + dy * c;
    }
}

__device__ __forceinline__ float rotated_iou_pair(const float* ab, const float* gb) {
    float ax[4], ay[4], gx[4], gy[4];
    float cA, sA, cG, sG;
    rect_corners5(ab, ax, ay, &cA, &sA);
    rect_corners5(gb, gx, gy, &cG, &sG);

    float rx[24], ry[24];
    unsigned msk = 0u;

#pragma unroll
    for (int i = 0; i < 4; ++i) {
        float dx = ax[i] - gb[0], dy = ay[i] - gb[1];
        float lx = dx * cG + dy * sG;
        float ly = -dx * sG + dy * cG;
        bool in = (fabsf(lx) <= 0.5f * gb[2] + 1e-4f) && (fabsf(ly) <= 0.5f * gb[3] + 1e-4f);
        rx[i] = ax[i]; ry[i] = ay[i];
        if (in) msk |= (1u << i);
    }
#pragma unroll
    for (int i = 0; i < 4; ++i) {
        float dx = gx[i] - ab[0], dy = gy[i] - ab[1];
        float lx = dx * cA + dy * sA;
        float ly = -dx * sA + dy * cA;
        bool in = (fabsf(lx) <= 0.5f * ab[2] + 1e-4f) && (fabsf(ly) <= 0.5f * ab[3] + 1e-4f);
        rx[4 + i] = gx[i]; ry[4 + i] = gy[i];
        if (in) msk |= (1u << (4 + i));
    }
#pragma unroll
    for (int i = 0; i < 4; ++i) {
        float p0x = ax[i], p0y = ay[i];
        float p1x = ax[(i + 1) & 3], p1y = ay[(i + 1) & 3];
        float d1x = p1x - p0x, d1y = p1y - p0y;
#pragma unroll
        for (int j = 0; j < 4; ++j) {
            float q0x = gx[j], q0y = gy[j];
            float q1x = gx[(j + 1) & 3], q1y = gy[(j + 1) & 3];
            float d2x = q1x - q0x, d2y = q1y - q0y;
            float rrx = q0x - p0x, rry = q0y - p0y;
            float den = d1x * d2y - d1y * d2x;
            float safe = (fabsf(den) < 1e-8f) ? 1.f : den;
            float t = (rrx * d2y - rry * d2x) / safe;
            float u = (rrx * d1y - rry * d1x) / safe;
            bool ok = (fabsf(den) >= 1e-8f) && (t >= 0.f) && (t <= 1.f) && (u >= 0.f) && (u <= 1.f);
            int k = 8 + i * 4 + j;
            rx[k] = p0x + t * d1x;
            ry[k] = p0y + t * d1y;
            if (ok) msk |= (1u << k);
        }
    }

    int cnt = __popc(msk);
    float sx = 0.f, sy = 0.f;
#pragma unroll
    for (int k = 0; k < 24; ++k)
        if ((msk >> k) & 1u) { sx += rx[k]; sy += ry[k]; }
    float cnf = fmaxf((float)cnt, 1.f);
    float cenx = sx / cnf, ceny = sy / cnf;

    float ang[24];
#pragma unroll
    for (int k = 0; k < 24; ++k) {
        if ((msk >> k) & 1u) {
            rx[k] -= cenx; ry[k] -= ceny;
            ang[k] = pseudo_angle(ry[k], rx[k]);
        } else {
            rx[k] = 0.f; ry[k] = 0.f;
            ang[k] = 1e9f;
        }
    }

    // stable argsort reproduced as rank with original-index tiebreak
    int rnk[24];
#pragma unroll
    for (int k = 0; k < 24; ++k) {
        int r = 0;
#pragma unroll
        for (int j = 0; j < 24; ++j)
            r += (ang[j] < ang[k]) || (ang[j] == ang[k] && j < k);
        rnk[k] = r;
    }

    // shoelace over sorted masked points. Unmasked j have rnk[j] >= cnt and
    // tgt < cnt, so the rnk[j]==tgt test alone suffices (no mask check).
    float ssum = 0.f;
#pragma unroll
    for (int k = 0; k < 24; ++k) {
        if ((msk >> k) & 1u) {
            int tgt = (rnk[k] + 1 == cnt) ? 0 : rnk[k] + 1;
            float qx = 0.f, qy = 0.f;
#pragma unroll
            for (int j = 0; j < 24; ++j) {
                if (rnk[j] == tgt) { qx = rx[j]; qy = ry[j]; }
            }
            ssum += rx[k] * qy - ry[k] * qx;
        }
    }
    float inter = (cnt >= 3) ? 0.5f * fabsf(ssum) : 0.f;
    float uni = ab[2] * ab[3] + gb[2] * gb[3] - inter;
    return inter / fmaxf(uni, 1e-8f);
}

// ---------------------------------------------------------------------------
// K1: gate. 128 blocks x 256 thr. Square-IoU gate -> per-block segment +
// count (deterministic, no global atomics). Light rowkey plain-stored to
// rowMaxArg (overwrites stale data -> no init kernel). Zeroes K3's counter.
// ---------------------------------------------------------------------------
__global__ void __launch_bounds__(256, 1)
gate_kernel(const float* __restrict__ anc,
            const float* __restrict__ ann,
            unsigned long long* __restrict__ rowMaxArg,
            unsigned* __restrict__ seg,
            unsigned* __restrict__ segcnt,
            unsigned* __restrict__ ctr) {
    __shared__ int ss[256];
    const int tid = threadIdx.x;
    const int t = blockIdx.x * 256 + tid;   // global anchor id
    const int b = blockIdx.x >> 6;          // 64 blocks per image

    if (blockIdx.x == 0 && tid == 0) ctr[0] = 0u;  // K3 arrival counter

    const float* ab = anc + (size_t)t * 5;
    float a0 = ab[0], a1 = ab[1], a2 = ab[2], a3 = ab[3];
    float sa = 0.5f * fmaxf(a2, a3);

    unsigned passmask = 0u;
    unsigned long long rk = 0ull;
#pragma unroll
    for (int g = 0; g < G_; ++g) {
        const float* gb = ann + ((size_t)b * G_ + g) * 6;  // uniform, cached
        float v;
        if (gb[5] == -1.0f) {
            v = -1.0f;
        } else {
            float sb = 0.5f * fmaxf(gb[2], gb[3]);
            float iw = fminf(a0 + sa, gb[0] + sb) - fmaxf(a0 - sa, gb[0] - sb);
            iw = fmaxf(iw, 0.f);
            float ih = fminf(a1 + sa, gb[1] + sb) - fmaxf(a1 - sa, gb[1] - sb);
            ih = fmaxf(ih, 0.f);
            float inter = iw * ih;
            float uni = 4.f * sa * sa + 4.f * sb * sb - inter;
            float ind = inter / fmaxf(uni, 1e-8f);
            if (ind > 0.1f) passmask |= (1u << g);
            v = 0.f;  // placeholder <= any heavy IoU, same tiebreak bits
        }
        unsigned long long key =
            ((unsigned long long)enc_f32(v) << 32) | (unsigned)(G_ - 1 - g);
        if (key > rk) rk = key;
    }
    rowMaxArg[t] = rk;   // plain store; K2 atomicMaxes heavy keys on top

    // block scan -> deterministic per-block segment
    int cnt = __popc(passmask);
    ss[tid] = cnt;
    __syncthreads();
    for (int s = 1; s < 256; s <<= 1) {
        int v = (tid >= s) ? ss[tid - s] : 0;
        __syncthreads();
        ss[tid] += v;
        __syncthreads();
    }
    unsigned p = (unsigned)(ss[tid] - cnt);
    unsigned* mySeg = seg + (size_t)blockIdx.x * SEGCAP;
#pragma unroll
    for (int g = 0; g < G_; ++g) {
        if ((passmask >> g) & 1u) mySeg[p++] = ((unsigned)tid << 4) | (unsigned)g;
    }
    if (tid == 0) segcnt[blockIdx.x] = (unsigned)ss[255];
}

// ---------------------------------------------------------------------------
// K2: heavy. 256 blocks x 128 thr, launch_bounds(128,1) -> 512-VGPR cap so
// the clip's ~100-float live set stays in registers. Every block scans the
// 128 segment counts in LDS; grid-stride over global item index + binary
// search -> perfect balance, <=1 clip per lane. Row keys: scattered global
// atomicMax over K1's light values. Col keys: LDS cells -> per-block
// partials. Max on monotone packed keys -> bit-deterministic.
// ---------------------------------------------------------------------------
__global__ void __launch_bounds__(128, 1)
heavy_kernel(const float* __restrict__ anc,
             const float* __restrict__ ann,
             const unsigned* __restrict__ seg,
             const unsigned* __restrict__ segcnt,
             unsigned long long* __restrict__ rowMaxArg,
             unsigned long long* __restrict__ partials) {
    __shared__ unsigned inc[NSEG];
    __shared__ unsigned long long cells[32];
    const int tid = threadIdx.x;

    if (tid < 32) cells[tid] = 0ull;
    inc[tid] = segcnt[tid];                // NSEG == blockDim.x == 128
    __syncthreads();
    for (int s = 1; s < NSEG; s <<= 1) {
        unsigned v = (tid >= s) ? inc[tid - s] : 0u;
        __syncthreads();
        inc[tid] += v;
        __syncthreads();
    }
    const unsigned n = inc[NSEG - 1];

    for (unsigned i = (unsigned)(blockIdx.x * 128 + tid); i < n; i += HB_ * 128) {
        // first segment s with inc[s] > i
        int lo = 0, hi = NSEG - 1;
        while (lo < hi) {
            int mid = (lo + hi) >> 1;
            if (inc[mid] > i) hi = mid; else lo = mid + 1;
        }
        unsigned base = (lo == 0) ? 0u : inc[lo - 1];
        unsigned e = seg[(size_t)lo * SEGCAP + (i - base)];
        int t2 = lo * 256 + (int)(e >> 4);
        int g = (int)(e & 15u);
        int b2 = t2 >> 14;
        const float* ab2 = anc + (size_t)t2 * 5;
        const float* gb2 = ann + ((size_t)b2 * G_ + g) * 6;
        float v = rotated_iou_pair(ab2, gb2);
        unsigned long long ev = (unsigned long long)enc_f32(v);
        atomicMax(&rowMaxArg[t2], (ev << 32) | (unsigned)(G_ - 1 - g));
        int aIdx = t2 & (A_ - 1);
        atomicMax(&cells[b2 * G_ + g], (ev << 32) | (0xFFFFFFFFu - (unsigned)aIdx));
    }
    __syncthreads();
    if (tid < 32) partials[(size_t)blockIdx.x * 32 + tid] = cells[tid];
}

// ---------------------------------------------------------------------------
// K3: colfinal + loss + final. 128 blocks x 256 thr.
// Each block redundantly reduces the HB_*32 col partials (L2-resident),
// computes per-anchor loss, writes block partials, and the last-arriving
// block does the deterministic ordered final combine (no spinning).
// ---------------------------------------------------------------------------
__global__ void __launch_bounds__(256, 1)
loss_kernel(const float* __restrict__ cls_p,
            const float* __restrict__ reg_p,
            const float* __restrict__ anc,
            const float* __restrict__ ann,
            const unsigned long long* __restrict__ rowMaxArg,
            const unsigned long long* __restrict__ partials,
            float* __restrict__ pcls,
            float* __restrict__ preg,
            int* __restrict__ pnp,
            unsigned* __restrict__ ctr,
            float* __restrict__ out) {
    __shared__ unsigned long long red[256];
    __shared__ unsigned long long pk32[32];
    __shared__ float sc[256], sr[256];
    __shared__ int sp[256];
    __shared__ int lastFlag;

    const int tid = threadIdx.x;

    // ---- colfinal: reduce HB_ x 32 partials; default candidate (0.0, a=0):
    // every non-heavy entry of a valid gt column is exactly 0.0 and anchor 0
    // is the smallest index, so colmax = max(best heavy, (0.0, anchor 0)).
    {
        int cell = tid & 31, chunk = tid >> 5;   // 8 chunks x 32 heavy-blocks
        unsigned long long m = 0ull;
        for (int blk = chunk * (HB_ / 8); blk < (chunk + 1) * (HB_ / 8); ++blk) {
            unsigned long long v = partials[(size_t)blk * 32 + cell];
            if (v > m) m = v;
        }
        red[tid] = m;
    }
    __syncthreads();
    if (tid < 32) {
        unsigned long long mm =
            ((unsigned long long)enc_f32(0.0f) << 32) | 0xFFFFFFFFu;
        for (int c = 0; c < 8; ++c) {
            unsigned long long v = red[c * 32 + tid];
            if (v > mm) mm = v;
        }
        pk32[tid] = mm;
    }
    __syncthreads();

    // ---- per-anchor loss ----
    const int t = blockIdx.x * 256 + tid;
    const int b = t >> 14;
    const int a = t & (A_ - 1);

    unsigned long long rk = rowMaxArg[t];
    unsigned ehi = (unsigned)(rk >> 32);
    int arg = (G_ - 1) - (int)(rk & 0xFu);

    bool forcedf = false;
#pragma unroll
    for (int g = 0; g < G_; ++g) {
        unsigned long long pkv = pk32[b * G_ + g];
        float lab = ann[((size_t)b * G_ + g) * 6 + 5];
        unsigned hi = (unsigned)(pkv >> 32);
        unsigned ai = 0xFFFFFFFFu - (unsigned)pkv;
        forcedf |= (lab != -1.0f) && (hi < ENC_HALF) && (ai == (unsigned)a);
    }

    bool pos = (ehi >= ENC_HALF) || forcedf;
    const float* g6 = ann + ((size_t)b * G_ + arg) * 6;
    int cls = (int)g6[5];

    float csum = 0.f;
    if (pos || ehi < ENC_04) {
        const float* pr = cls_p + (size_t)t * C_;
#pragma unroll
        for (int c = 0; c < C_; ++c) {
            float tgt = (pos && c == cls) ? 1.f : 0.f;
            float pv = fminf(fmaxf(pr[c], 1e-4f), 1.f - 1e-4f);
            float af = (tgt == 1.f) ? 0.25f : 0.75f;
            float x = (tgt == 1.f) ? (1.f - pv) : pv;
            float fw = af * x * x;
            float bce = -(tgt * logf(pv + 1e-6f) + (1.f - tgt) * logf(1.f - pv + 1e-6f));
            csum += fw * bce;
        }
    }

    float rsum = 0.f;
    if (pos) {
        const float* ex = anc + (size_t)t * 5;
        const float* rp = reg_p + (size_t)t * 5;
        float ew = fmaxf(ex[2], 1.f), eh2 = fmaxf(ex[3], 1.f);
        float gw = fmaxf(g6[2], 1.f), gh = fmaxf(g6[3], 1.f);
        float tg[5];
        tg[0] = 10.f * (g6[0] - ex[0]) / ew;
        tg[1] = 10.f * (g6[1] - ex[1]) / eh2;
        tg[2] = 10.f * logf(gw / ew);
        tg[3] = 5.f * logf(gh / eh2);
        tg[4] = 15.f * (tanf(g6[4] * D2Rf) - tanf(ex[4] * D2Rf));
        const float BETAf = (float)(1.0 / 9.0);
#pragma unroll
        for (int i = 0; i < 5; ++i) {
            float d = fabsf(rp[i] - tg[i]);
            rsum += (d < BETAf) ? 0.5f * d * d / BETAf : d - 0.5f * BETAf;
        }
    }

    sc[tid] = csum; sr[tid] = rsum; sp[tid] = pos ? 1 : 0;
    __syncthreads();
    for (int s = 128; s > 0; s >>= 1) {
        if (tid < s) {
            sc[tid] += sc[tid + s];
            sr[tid] += sr[tid + s];
            sp[tid] += sp[tid + s];
        }
        __syncthreads();
    }
    if (tid == 0) {
        pcls[blockIdx.x] = sc[0];
        preg[blockIdx.x] = sr[0];
        pnp[blockIdx.x] = sp[0];
        __threadfence();   // release partials (writeback to coherent point)
        unsigned v = atomicAdd(ctr, 1u);   // single RMW, no spinning
        lastFlag = (v == (unsigned)(LB_ - 1));
    }
    __syncthreads();

    // ---- last-arriving block: deterministic ordered final combine ----
    if (lastFlag) {
        __threadfence();   // acquire (invalidate local caches)
        if (tid < LB_) {
            sc[tid] = pcls[tid];
            sr[tid] = preg[tid];
            sp[tid] = pnp[tid];
        }
        __syncthreads();
        if (tid == 0) {
            const int BPI = LB_ / B_;   // 64 blocks per image
            float cm = 0.f, rm = 0.f;
            for (int bb = 0; bb < B_; ++bb) {
                float cs = 0.f, rs = 0.f; int np = 0;
                for (int i = 0; i < BPI; ++i) {
                    cs += sc[bb * BPI + i];
                    rs += sr[bb * BPI + i];
                    np += sp[bb * BPI + i];
                }
                bool has = false;
                for (int g = 0; g < G_; ++g)
                    if (ann[((size_t)bb * G_ + g) * 6 + 5] != -1.0f) has = true;
                float c_ = cs / fmaxf((float)np, 1.f);
                int d5 = np * 5; if (d5 < 1) d5 = 1;
                float r_ = (np > 0) ? rs / (float)d5 : 0.f;
                cm += has ? c_ : 0.f;
                rm += has ? r_ : 0.f;
            }
            out[0] = cm / (float)B_;
            out[1] = rm / (float)B_;
        }
    }
}

// ---------------------------------------------------------------------------
extern "C" void kernel_launch(void* const* d_in, const int* in_sizes, int n_in,
                              void* d_out, int out_size, void* d_ws, size_t ws_size,
                              hipStream_t stream) {
    const float* cls_p = (const float*)d_in[0];   // (B,A,C)
    const float* reg_p = (const float*)d_in[1];   // (B,A,5)
    const float* anc   = (const float*)d_in[2];   // (B,A,5)
    const float* ann   = (const float*)d_in[3];   // (B,G,6)
    float* out = (float*)d_out;

    // workspace (every word consumed is rewritten each call; no memset)
    char* ws = (char*)d_ws;
    unsigned* ctrp = (unsigned*)ws;                                   // 256 B
    unsigned long long* rowMaxArg = (unsigned long long*)(ws + 256);  // 256 KB
    unsigned long long* partials = rowMaxArg + (size_t)B_ * A_;       // HB_*32*8 = 64 KB
    unsigned* segcnt = (unsigned*)(partials + (size_t)HB_ * 32);      // NSEG u32
    unsigned* seg    = segcnt + NSEG;                                 // NSEG*SEGCAP*4 = 2 MB
    float* pcls = (float*)(seg + (size_t)NSEG * SEGCAP);              // LB_
    float* preg = pcls + LB_;
    int*   pnp  = (int*)(preg + LB_);

    gate_kernel<<<NSEG, 256, 0, stream>>>(anc, ann, rowMaxArg, seg, segcnt, ctrp);
    heavy_kernel<<<HB_, 128, 0, stream>>>(anc, ann, seg, segcnt, rowMaxArg, partials);
    loss_kernel<<<LB_, 256, 0, stream>>>(cls_p, reg_p, anc, ann, rowMaxArg,
                                         partials, pcls, preg, pnp, ctrp, out);
}